// Round 1
// baseline (421.128 us; speedup 1.0000x reference)
//
#include <hip/hip_runtime.h>
#include <math.h>

#define S_LEN 4096
#define DM 1024
#define NHEADS 8
#define HDIM 128
#define NSLOTS 2048

typedef __attribute__((ext_vector_type(8))) short bf16x8;
typedef __attribute__((ext_vector_type(4))) float f32x4;

static __device__ __forceinline__ unsigned short f2bf(float f) {
  union { float f; unsigned u; } v; v.f = f;
  unsigned u = v.u;
  return (unsigned short)((u + 0x7fffu + ((u >> 16) & 1u)) >> 16);
}
static __device__ __forceinline__ unsigned pack2(float a, float b) {
  return (unsigned)f2bf(a) | ((unsigned)f2bf(b) << 16);
}
static __device__ __forceinline__ f32x4 mfma16(bf16x8 a, bf16x8 b, f32x4 c) {
  return __builtin_amdgcn_mfma_f32_16x16x32_bf16(a, b, c, 0, 0, 0);
}
static __device__ __forceinline__ void gll16(const void* g, void* l) {
  __builtin_amdgcn_global_load_lds(
      (__attribute__((address_space(1))) void*)(void*)(unsigned long long)(const char*)g,
      (__attribute__((address_space(3))) void*)l, 16, 0, 0);
}

// ---- prep kernels -----------------------------------------------------------

__global__ __launch_bounds__(256) void cast_x_kernel(const float* __restrict__ x,
                                                     unsigned* __restrict__ xb, int n2) {
  int i = blockIdx.x * blockDim.x + threadIdx.x;
  if (i < n2) {
    float2 v = ((const float2*)x)[i];
    xb[i] = pack2(v.x, v.y);
  }
}

// WT[n][k] = bf16(W[k][n]), 1024x1024
__global__ __launch_bounds__(256) void transpose_cast_kernel(const float* __restrict__ W,
                                                             unsigned short* __restrict__ WT) {
  __shared__ float tile[32][33];
  int n0 = blockIdx.x * 32, k0 = blockIdx.y * 32;
  int tx = threadIdx.x & 31, ty = threadIdx.x >> 5;
#pragma unroll
  for (int i = ty; i < 32; i += 8) tile[i][tx] = W[(k0 + i) * DM + n0 + tx];
  __syncthreads();
#pragma unroll
  for (int i = ty; i < 32; i += 8) WT[(n0 + i) * DM + k0 + tx] = f2bf(tile[tx][i]);
}

// kbf[h][slot][d] = bf16(normalize(keys[slot*8+h]) * attn_scale[h])
__global__ __launch_bounds__(256) void prep_k_kernel(const float* __restrict__ keys,
                                                     const float* __restrict__ scale,
                                                     unsigned* __restrict__ kbf) {
  int w = (blockIdx.x * 256 + threadIdx.x) >> 6;  // row 0..16383
  int lane = threadIdx.x & 63;
  int slot = w >> 3, h = w & 7;
  float2 v = ((const float2*)(keys + (size_t)w * HDIM))[lane];
  float ss = v.x * v.x + v.y * v.y;
#pragma unroll
  for (int m = 1; m < 64; m <<= 1) ss += __shfl_xor(ss, m);
  float sc = scale[h] * rsqrtf(ss + 1e-6f);
  kbf[((size_t)h * NSLOTS + slot) * (HDIM / 2) + lane] = pack2(v.x * sc, v.y * sc);
}

// vt[h][d][slot] = bf16(values[slot*8+h][d])   (transposed for PV B-fragments)
__global__ __launch_bounds__(256) void prep_vt_kernel(const float* __restrict__ values,
                                                      unsigned short* __restrict__ vt) {
  __shared__ float tile[32][33];
  int h = blockIdx.z;
  int s0 = blockIdx.x * 32, d0 = blockIdx.y * 32;
  int tx = threadIdx.x & 31, ty = threadIdx.x >> 5;
#pragma unroll
  for (int i = ty; i < 32; i += 8)
    tile[i][tx] = values[((size_t)(s0 + i) * NHEADS + h) * HDIM + d0 + tx];  // [slot][d]
  __syncthreads();
#pragma unroll
  for (int i = ty; i < 32; i += 8)
    vt[((size_t)h * HDIM + d0 + i) * NSLOTS + s0 + tx] = f2bf(tile[tx][i]);
}

// qbf = bf16(normalize per 128-chunk of qf)
__global__ __launch_bounds__(256) void norm_q_kernel(const float* __restrict__ qf,
                                                     unsigned* __restrict__ qbf) {
  int w = (blockIdx.x * 256 + threadIdx.x) >> 6;  // (s,h) row 0..32767
  int lane = threadIdx.x & 63;
  float2 v = ((const float2*)(qf + (size_t)w * HDIM))[lane];
  float ss = v.x * v.x + v.y * v.y;
#pragma unroll
  for (int m = 1; m < 64; m <<= 1) ss += __shfl_xor(ss, m);
  float rs = rsqrtf(ss + 1e-6f);
  qbf[(size_t)w * (HDIM / 2) + lane] = pack2(v.x * rs, v.y * rs);
}

// ---- GEMM: C(MxN,f32) = A(MxK,bf16 rowmajor) * Bt(NxK,bf16 rowmajor)^T ------
// 128x128 block tile, 4 waves each 64x64, BK=32, global_load_lds staging.
__global__ __launch_bounds__(256) void gemm_nt_kernel(const unsigned short* __restrict__ A,
                                                      const unsigned short* __restrict__ Bt,
                                                      float* __restrict__ C,
                                                      int M, int N, int K) {
  __shared__ unsigned short As[128 * 32];
  __shared__ unsigned short Bs[128 * 32];
  int t = threadIdx.x;
  int wave = t >> 6, lane = t & 63;
  int l16 = lane & 15, quad = lane >> 4;
  int m_blk = blockIdx.y * 128, n_blk = blockIdx.x * 128;
  int wm = (wave & 1) * 64, wn = (wave >> 1) * 64;
  int sm = t >> 2, sk = (t & 3) * 8;
  const unsigned short* Ap = A + (size_t)(m_blk + sm) * K + sk;
  const unsigned short* Bp = Bt + (size_t)(n_blk + sm) * K + sk;
  unsigned short* AsW = As + wave * 512;
  unsigned short* BsW = Bs + wave * 512;
  f32x4 zero = {0.f, 0.f, 0.f, 0.f};
  f32x4 acc[4][4];
#pragma unroll
  for (int i = 0; i < 4; i++)
#pragma unroll
    for (int j = 0; j < 4; j++) acc[i][j] = zero;

  for (int k0 = 0; k0 < K; k0 += 32) {
    __syncthreads();
    gll16(Ap + k0, AsW);
    gll16(Ap + (size_t)64 * K + k0, AsW + 2048);
    gll16(Bp + k0, BsW);
    gll16(Bp + (size_t)64 * K + k0, BsW + 2048);
    __syncthreads();
    bf16x8 af[4], bfr[4];
#pragma unroll
    for (int mt = 0; mt < 4; mt++)
      af[mt] = *(const bf16x8*)(As + (wm + mt * 16 + l16) * 32 + quad * 8);
#pragma unroll
    for (int nt = 0; nt < 4; nt++)
      bfr[nt] = *(const bf16x8*)(Bs + (wn + nt * 16 + l16) * 32 + quad * 8);
#pragma unroll
    for (int mt = 0; mt < 4; mt++)
#pragma unroll
      for (int nt = 0; nt < 4; nt++) acc[mt][nt] = mfma16(af[mt], bfr[nt], acc[mt][nt]);
  }
#pragma unroll
  for (int mt = 0; mt < 4; mt++)
#pragma unroll
    for (int nt = 0; nt < 4; nt++)
#pragma unroll
      for (int r = 0; r < 4; r++)
        C[(size_t)(m_blk + wm + mt * 16 + quad * 4 + r) * N + n_blk + wn + nt * 16 + l16] =
            acc[mt][nt][r];
}

// ---- flash attention vs fixed memory bank -----------------------------------
// grid (S/64, H); 4 waves x 16 q-rows. Online softmax; P goes C-layout -> LDS
// (row pad +8 bf16 => 2-way conflicts = free) -> A-layout for PV.
__global__ __launch_bounds__(256) void attn_kernel(const unsigned short* __restrict__ qbf,
                                                   const unsigned short* __restrict__ kbf,
                                                   const unsigned short* __restrict__ vt,
                                                   unsigned short* __restrict__ yb) {
  __shared__ unsigned short pbuf[4][16][72];
  int h = blockIdx.y;
  int wave = threadIdx.x >> 6, lane = threadIdx.x & 63;
  int l16 = lane & 15, quad = lane >> 4;
  int m0 = blockIdx.x * 64 + wave * 16;
  const unsigned short* Kh = kbf + (size_t)h * NSLOTS * HDIM;
  const unsigned short* Vh = vt + (size_t)h * HDIM * NSLOTS;

  bf16x8 aq[4];
  const unsigned short* qrow = qbf + (size_t)(m0 + l16) * DM + h * HDIM + quad * 8;
#pragma unroll
  for (int dt = 0; dt < 4; dt++) aq[dt] = *(const bf16x8*)(qrow + dt * 32);

  f32x4 zero = {0.f, 0.f, 0.f, 0.f};
  f32x4 O[8];
#pragma unroll
  for (int i = 0; i < 8; i++) O[i] = zero;
  float m_i[4], l_i[4];
#pragma unroll
  for (int r = 0; r < 4; r++) { m_i[r] = -INFINITY; l_i[r] = 0.f; }

  for (int n0 = 0; n0 < NSLOTS; n0 += 64) {
    f32x4 Sf[4];
#pragma unroll
    for (int nt = 0; nt < 4; nt++) {
      f32x4 a = zero;
      const unsigned short* krow = Kh + (size_t)(n0 + nt * 16 + l16) * HDIM + quad * 8;
#pragma unroll
      for (int dt = 0; dt < 4; dt++) a = mfma16(aq[dt], *(const bf16x8*)(krow + dt * 32), a);
      Sf[nt] = a;
    }
    float alpha[4], lsum[4];
#pragma unroll
    for (int r = 0; r < 4; r++) {
      float m = fmaxf(fmaxf(Sf[0][r], Sf[1][r]), fmaxf(Sf[2][r], Sf[3][r]));
#pragma unroll
      for (int d = 1; d < 16; d <<= 1) m = fmaxf(m, __shfl_xor(m, d));
      m = fmaxf(m, m_i[r]);
      alpha[r] = __expf(m_i[r] - m);
      m_i[r] = m;
      lsum[r] = 0.f;
    }
#pragma unroll
    for (int nt = 0; nt < 4; nt++)
#pragma unroll
      for (int r = 0; r < 4; r++) {
        float p = __expf(Sf[nt][r] - m_i[r]);
        Sf[nt][r] = p;
        lsum[r] += p;
      }
#pragma unroll
    for (int r = 0; r < 4; r++) {
      float s = lsum[r];
#pragma unroll
      for (int d = 1; d < 16; d <<= 1) s += __shfl_xor(s, d);
      l_i[r] = l_i[r] * alpha[r] + s;
    }
#pragma unroll
    for (int dt = 0; dt < 8; dt++)
#pragma unroll
      for (int r = 0; r < 4; r++) O[dt][r] *= alpha[r];

    __syncthreads();
#pragma unroll
    for (int nt = 0; nt < 4; nt++)
#pragma unroll
      for (int r = 0; r < 4; r++)
        pbuf[wave][quad * 4 + r][nt * 16 + l16] = f2bf(Sf[nt][r]);
    __syncthreads();

    bf16x8 ap[2];
#pragma unroll
    for (int kc = 0; kc < 2; kc++)
      ap[kc] = *(const bf16x8*)(&pbuf[wave][l16][kc * 32 + quad * 8]);
#pragma unroll
    for (int dt = 0; dt < 8; dt++) {
      f32x4 a = O[dt];
#pragma unroll
      for (int kc = 0; kc < 2; kc++) {
        const unsigned short* vrow =
            Vh + (size_t)(dt * 16 + l16) * NSLOTS + n0 + kc * 32 + quad * 8;
        a = mfma16(ap[kc], *(const bf16x8*)vrow, a);
      }
      O[dt] = a;
    }
  }
#pragma unroll
  for (int r = 0; r < 4; r++) l_i[r] = 1.f / l_i[r];
#pragma unroll
  for (int dt = 0; dt < 8; dt++)
#pragma unroll
    for (int r = 0; r < 4; r++)
      yb[(size_t)(m0 + quad * 4 + r) * DM + h * HDIM + dt * 16 + l16] =
          f2bf(O[dt][r] * l_i[r]);
}

// ---- launcher ---------------------------------------------------------------

extern "C" void kernel_launch(void* const* d_in, const int* in_sizes, int n_in,
                              void* d_out, int out_size, void* d_ws, size_t ws_size,
                              hipStream_t stream) {
  const float* x = (const float*)d_in[0];
  const float* Wq = (const float*)d_in[1];
  const float* keys = (const float*)d_in[2];
  const float* values = (const float*)d_in[3];
  const float* attn_scale = (const float*)d_in[4];
  const float* Wo = (const float*)d_in[5];
  float* out = (float*)d_out;

  char* ws = (char*)d_ws;
  unsigned short* xb = (unsigned short*)(ws);                      // 8 MB
  unsigned short* wqt = (unsigned short*)(ws + (8ull << 20));      // 2 MB
  unsigned short* wot = (unsigned short*)(ws + (10ull << 20));     // 2 MB
  unsigned short* kbf = (unsigned short*)(ws + (12ull << 20));     // 4 MB
  unsigned short* vt = (unsigned short*)(ws + (16ull << 20));      // 4 MB
  float* qf = (float*)(ws + (20ull << 20));                        // 16 MB
  unsigned short* qbf = (unsigned short*)(ws + (36ull << 20));     // 8 MB
  unsigned short* yb = (unsigned short*)(ws + (44ull << 20));      // 8 MB  (total 52 MB)

  cast_x_kernel<<<8192, 256, 0, stream>>>(x, (unsigned*)xb, (S_LEN * DM) / 2);
  transpose_cast_kernel<<<dim3(32, 32), 256, 0, stream>>>(Wq, wqt);
  transpose_cast_kernel<<<dim3(32, 32), 256, 0, stream>>>(Wo, wot);
  prep_k_kernel<<<4096, 256, 0, stream>>>(keys, attn_scale, (unsigned*)kbf);
  prep_vt_kernel<<<dim3(64, 4, 8), 256, 0, stream>>>(values, vt);
  gemm_nt_kernel<<<dim3(8, 32), 256, 0, stream>>>(xb, wqt, qf, S_LEN, DM, DM);
  norm_q_kernel<<<8192, 256, 0, stream>>>(qf, (unsigned*)qbf);
  attn_kernel<<<dim3(64, 8), 256, 0, stream>>>(qbf, kbf, vt, yb);
  gemm_nt_kernel<<<dim3(8, 32), 256, 0, stream>>>(yb, wot, out, S_LEN, DM, DM);
}

// Round 2
// 236.132 us; speedup vs baseline: 1.7834x; 1.7834x over previous
//
#include <hip/hip_runtime.h>
#include <math.h>

#define S_LEN 4096
#define DM 1024
#define NHEADS 8
#define HDIM 128
#define NSLOTS 2048

typedef __attribute__((ext_vector_type(8))) short bf16x8;
typedef __attribute__((ext_vector_type(4))) float f32x4;

static __device__ __forceinline__ unsigned short f2bf(float f) {
  union { float f; unsigned u; } v; v.f = f;
  unsigned u = v.u;
  return (unsigned short)((u + 0x7fffu + ((u >> 16) & 1u)) >> 16);
}
static __device__ __forceinline__ unsigned pack2(float a, float b) {
  return (unsigned)f2bf(a) | ((unsigned)f2bf(b) << 16);
}
static __device__ __forceinline__ f32x4 mfma16(bf16x8 a, bf16x8 b, f32x4 c) {
  return __builtin_amdgcn_mfma_f32_16x16x32_bf16(a, b, c, 0, 0, 0);
}
static __device__ __forceinline__ void gll16(const void* g, void* l) {
  __builtin_amdgcn_global_load_lds(
      (__attribute__((address_space(1))) void*)(void*)(unsigned long long)(const char*)g,
      (__attribute__((address_space(3))) void*)l, 16, 0, 0);
}

// ---- prep kernels -----------------------------------------------------------

__global__ __launch_bounds__(256) void cast_x_kernel(const float* __restrict__ x,
                                                     unsigned* __restrict__ xb, int n2) {
  int i = blockIdx.x * blockDim.x + threadIdx.x;
  if (i < n2) {
    float2 v = ((const float2*)x)[i];
    xb[i] = pack2(v.x, v.y);
  }
}

// WT[n][k] = bf16(W[k][n]), 1024x1024
__global__ __launch_bounds__(256) void transpose_cast_kernel(const float* __restrict__ W,
                                                             unsigned short* __restrict__ WT) {
  __shared__ float tile[32][33];
  int n0 = blockIdx.x * 32, k0 = blockIdx.y * 32;
  int tx = threadIdx.x & 31, ty = threadIdx.x >> 5;
#pragma unroll
  for (int i = ty; i < 32; i += 8) tile[i][tx] = W[(k0 + i) * DM + n0 + tx];
  __syncthreads();
#pragma unroll
  for (int i = ty; i < 32; i += 8) WT[(n0 + i) * DM + k0 + tx] = f2bf(tile[tx][i]);
}

// kbf[h][slot][d] = bf16(normalize(keys[slot*8+h]) * attn_scale[h])
__global__ __launch_bounds__(256) void prep_k_kernel(const float* __restrict__ keys,
                                                     const float* __restrict__ scale,
                                                     unsigned* __restrict__ kbf) {
  int w = (blockIdx.x * 256 + threadIdx.x) >> 6;  // row 0..16383
  int lane = threadIdx.x & 63;
  int slot = w >> 3, h = w & 7;
  float2 v = ((const float2*)(keys + (size_t)w * HDIM))[lane];
  float ss = v.x * v.x + v.y * v.y;
#pragma unroll
  for (int m = 1; m < 64; m <<= 1) ss += __shfl_xor(ss, m);
  float sc = scale[h] * rsqrtf(ss + 1e-6f);
  kbf[((size_t)h * NSLOTS + slot) * (HDIM / 2) + lane] = pack2(v.x * sc, v.y * sc);
}

// vt[h][d][slot] = bf16(values[slot*8+h][d])   (transposed for PV B-fragments)
__global__ __launch_bounds__(256) void prep_vt_kernel(const float* __restrict__ values,
                                                      unsigned short* __restrict__ vt) {
  __shared__ float tile[32][33];
  int h = blockIdx.z;
  int s0 = blockIdx.x * 32, d0 = blockIdx.y * 32;
  int tx = threadIdx.x & 31, ty = threadIdx.x >> 5;
#pragma unroll
  for (int i = ty; i < 32; i += 8)
    tile[i][tx] = values[((size_t)(s0 + i) * NHEADS + h) * HDIM + d0 + tx];  // [slot][d]
  __syncthreads();
#pragma unroll
  for (int i = ty; i < 32; i += 8)
    vt[((size_t)h * HDIM + d0 + i) * NSLOTS + s0 + tx] = f2bf(tile[tx][i]);
}

// qbf = bf16(normalize per 128-chunk of qf)
__global__ __launch_bounds__(256) void norm_q_kernel(const float* __restrict__ qf,
                                                     unsigned* __restrict__ qbf) {
  int w = (blockIdx.x * 256 + threadIdx.x) >> 6;  // (s,h) row 0..32767
  int lane = threadIdx.x & 63;
  float2 v = ((const float2*)(qf + (size_t)w * HDIM))[lane];
  float ss = v.x * v.x + v.y * v.y;
#pragma unroll
  for (int m = 1; m < 64; m <<= 1) ss += __shfl_xor(ss, m);
  float rs = rsqrtf(ss + 1e-6f);
  qbf[(size_t)w * (HDIM / 2) + lane] = pack2(v.x * rs, v.y * rs);
}

// ---- GEMM: C(MxN,f32) = A(MxK,bf16 rowmajor) * Bt(NxK,bf16 rowmajor)^T ------
__global__ __launch_bounds__(256) void gemm_nt_kernel(const unsigned short* __restrict__ A,
                                                      const unsigned short* __restrict__ Bt,
                                                      float* __restrict__ C,
                                                      int M, int N, int K) {
  __shared__ unsigned short As[128 * 32];
  __shared__ unsigned short Bs[128 * 32];
  int t = threadIdx.x;
  int wave = t >> 6, lane = t & 63;
  int l16 = lane & 15, quad = lane >> 4;
  int m_blk = blockIdx.y * 128, n_blk = blockIdx.x * 128;
  int wm = (wave & 1) * 64, wn = (wave >> 1) * 64;
  int sm = t >> 2, sk = (t & 3) * 8;
  const unsigned short* Ap = A + (size_t)(m_blk + sm) * K + sk;
  const unsigned short* Bp = Bt + (size_t)(n_blk + sm) * K + sk;
  unsigned short* AsW = As + wave * 512;
  unsigned short* BsW = Bs + wave * 512;
  f32x4 zero = {0.f, 0.f, 0.f, 0.f};
  f32x4 acc[4][4];
#pragma unroll
  for (int i = 0; i < 4; i++)
#pragma unroll
    for (int j = 0; j < 4; j++) acc[i][j] = zero;

  for (int k0 = 0; k0 < K; k0 += 32) {
    __syncthreads();
    gll16(Ap + k0, AsW);
    gll16(Ap + (size_t)64 * K + k0, AsW + 2048);
    gll16(Bp + k0, BsW);
    gll16(Bp + (size_t)64 * K + k0, BsW + 2048);
    __syncthreads();
    bf16x8 af[4], bfr[4];
#pragma unroll
    for (int mt = 0; mt < 4; mt++)
      af[mt] = *(const bf16x8*)(As + (wm + mt * 16 + l16) * 32 + quad * 8);
#pragma unroll
    for (int nt = 0; nt < 4; nt++)
      bfr[nt] = *(const bf16x8*)(Bs + (wn + nt * 16 + l16) * 32 + quad * 8);
#pragma unroll
    for (int mt = 0; mt < 4; mt++)
#pragma unroll
      for (int nt = 0; nt < 4; nt++) acc[mt][nt] = mfma16(af[mt], bfr[nt], acc[mt][nt]);
  }
#pragma unroll
  for (int mt = 0; mt < 4; mt++)
#pragma unroll
    for (int nt = 0; nt < 4; nt++)
#pragma unroll
      for (int r = 0; r < 4; r++)
        C[(size_t)(m_blk + wm + mt * 16 + quad * 4 + r) * N + n_blk + wn + nt * 16 + l16] =
            acc[mt][nt][r];
}

// ---- flash attention vs fixed memory bank -----------------------------------
// grid (H, S/64); 4 waves x 16 q-rows. LDS-staged K/V (double-buffered, 32-slot
// chunks, global_load_lds w16, XOR-swizzled 16B blocks -> conflict-free b128).
// Static softmax max M=|scale_h| (|q.k| <= |scale|) -> no online rescaling.
__global__ __launch_bounds__(256, 4) void attn_kernel(const unsigned short* __restrict__ qbf,
                                                      const unsigned short* __restrict__ kbf,
                                                      const unsigned short* __restrict__ vt,
                                                      const float* __restrict__ scale,
                                                      unsigned short* __restrict__ yb) {
  __shared__ unsigned short Ks[2][32 * 128];   // [slot][d], blocks swizzled j^=(r&15)
  __shared__ unsigned short Vs[2][64 * 64];    // row rr=d>>1, col=(d&1)*32+slot, cb^=(rr&7)
  __shared__ unsigned short pbuf[4][16][40];   // P transpose buffer, row stride 80B
  int h = blockIdx.x;
  int t = threadIdx.x;
  int wave = t >> 6, lane = t & 63;
  int l16 = lane & 15, quad = lane >> 4;
  int m0 = blockIdx.y * 64 + wave * 16;
  const unsigned short* Kh = kbf + (size_t)h * NSLOTS * HDIM;
  const unsigned short* Vh = vt + (size_t)h * HDIM * NSLOTS;
  float M = fabsf(scale[h]);

  bf16x8 aq[4];
  const unsigned short* qrow = qbf + (size_t)(m0 + l16) * DM + h * HDIM + quad * 8;
#pragma unroll
  for (int dt = 0; dt < 4; dt++) aq[dt] = *(const bf16x8*)(qrow + dt * 32);

  // staging address precompute (per-thread, chunk-invariant)
  int kr = t >> 4;                                  // K row within call-group
  int kcol = ((t & 15) ^ kr) * 8;                   // swizzled col block
  const unsigned short* KgBase = Kh + (size_t)kr * HDIM + kcol;
  int vcb = (t & 7) ^ ((t >> 3) & 7);               // swizzled V col block
  int vd = (t >> 3) * 2 + (vcb >> 2);
  const unsigned short* VgBase = Vh + (size_t)vd * NSLOTS + (vcb & 3) * 8;

  f32x4 zero = {0.f, 0.f, 0.f, 0.f};
  f32x4 O[8];
#pragma unroll
  for (int i = 0; i < 8; i++) O[i] = zero;
  float lsum[4] = {0.f, 0.f, 0.f, 0.f};

  auto stage = [&](int n0s, int b) {
    unsigned short* Kl = &Ks[b][0] + wave * 512;
    unsigned short* Vl = &Vs[b][0] + wave * 512;
    const unsigned short* Kg = KgBase + (size_t)n0s * HDIM;
    const unsigned short* Vg = VgBase + n0s;
#pragma unroll
    for (int c2 = 0; c2 < 2; c2++) {
      gll16(Kg + (size_t)c2 * 16 * HDIM, Kl + c2 * 2048);
      gll16(Vg + (size_t)c2 * 64 * NSLOTS, Vl + c2 * 2048);
    }
  };

  stage(0, 0);
  for (int c = 0; c < NSLOTS / 32; c++) {
    int b = c & 1;
    __syncthreads();  // drains DMA for chunk c; all waves done with chunk c-1
    if (c + 1 < NSLOTS / 32) stage((c + 1) * 32, b ^ 1);

    const unsigned short* Kb = &Ks[b][0];
    const unsigned short* Vb = &Vs[b][0];
    f32x4 Sf[2];
#pragma unroll
    for (int nt = 0; nt < 2; nt++) {
      f32x4 a = zero;
      const unsigned short* Krow = Kb + (nt * 16 + l16) * 128;
#pragma unroll
      for (int dt = 0; dt < 4; dt++)
        a = mfma16(aq[dt], *(const bf16x8*)(Krow + (((dt * 4 + quad) ^ l16) * 8)), a);
      Sf[nt] = a;
    }
#pragma unroll
    for (int nt = 0; nt < 2; nt++)
#pragma unroll
      for (int r = 0; r < 4; r++) {
        float p = __expf(Sf[nt][r] - M);
        lsum[r] += p;
        pbuf[wave][quad * 4 + r][nt * 16 + l16] = f2bf(p);
      }
    bf16x8 ap = *(const bf16x8*)(&pbuf[wave][l16][quad * 8]);
#pragma unroll
    for (int dt = 0; dt < 8; dt++) {
      int rr = dt * 8 + (l16 >> 1);
      const unsigned short* vptr =
          Vb + (rr * 8 + (((l16 & 1) * 4 + quad) ^ (l16 >> 1))) * 8;
      O[dt] = mfma16(ap, *(const bf16x8*)vptr, O[dt]);
    }
  }

  float inv[4];
#pragma unroll
  for (int r = 0; r < 4; r++) {
    float s = lsum[r];
#pragma unroll
    for (int d = 1; d < 16; d <<= 1) s += __shfl_xor(s, d);
    inv[r] = 1.0f / s;
  }
#pragma unroll
  for (int dt = 0; dt < 8; dt++)
#pragma unroll
    for (int r = 0; r < 4; r++)
      yb[(size_t)(m0 + quad * 4 + r) * DM + h * HDIM + dt * 16 + l16] =
          f2bf(O[dt][r] * inv[r]);
}

// ---- launcher ---------------------------------------------------------------

extern "C" void kernel_launch(void* const* d_in, const int* in_sizes, int n_in,
                              void* d_out, int out_size, void* d_ws, size_t ws_size,
                              hipStream_t stream) {
  const float* x = (const float*)d_in[0];
  const float* Wq = (const float*)d_in[1];
  const float* keys = (const float*)d_in[2];
  const float* values = (const float*)d_in[3];
  const float* attn_scale = (const float*)d_in[4];
  const float* Wo = (const float*)d_in[5];
  float* out = (float*)d_out;

  char* ws = (char*)d_ws;
  unsigned short* xb = (unsigned short*)(ws);                      // 8 MB
  unsigned short* wqt = (unsigned short*)(ws + (8ull << 20));      // 2 MB
  unsigned short* wot = (unsigned short*)(ws + (10ull << 20));     // 2 MB
  unsigned short* kbf = (unsigned short*)(ws + (12ull << 20));     // 4 MB
  unsigned short* vt = (unsigned short*)(ws + (16ull << 20));      // 4 MB
  float* qf = (float*)(ws + (20ull << 20));                        // 16 MB
  unsigned short* qbf = (unsigned short*)(ws + (36ull << 20));     // 8 MB
  unsigned short* yb = (unsigned short*)(ws + (44ull << 20));      // 8 MB

  cast_x_kernel<<<8192, 256, 0, stream>>>(x, (unsigned*)xb, (S_LEN * DM) / 2);
  transpose_cast_kernel<<<dim3(32, 32), 256, 0, stream>>>(Wq, wqt);
  transpose_cast_kernel<<<dim3(32, 32), 256, 0, stream>>>(Wo, wot);
  prep_k_kernel<<<4096, 256, 0, stream>>>(keys, attn_scale, (unsigned*)kbf);
  prep_vt_kernel<<<dim3(64, 4, 8), 256, 0, stream>>>(values, vt);
  gemm_nt_kernel<<<dim3(8, 32), 256, 0, stream>>>(xb, wqt, qf, S_LEN, DM, DM);
  norm_q_kernel<<<8192, 256, 0, stream>>>(qf, (unsigned*)qbf);
  attn_kernel<<<dim3(8, 64), 256, 0, stream>>>(qbf, kbf, vt, attn_scale, yb);
  gemm_nt_kernel<<<dim3(8, 32), 256, 0, stream>>>(yb, wot, out, S_LEN, DM, DM);
}